// Round 10
// baseline (277.540 us; speedup 1.0000x reference)
//
#include <hip/hip_runtime.h>
#include <math.h>

#define BDIM 2
#define TT 1024
#define NH 8
#define HD 64
#define NTOPK 16
#define NBH 16     // BDIM*NH
#define NTOK 16384 // NBH*TT

// ---------------------------------------------------------------------------
// Collapse the linear-linear pair MLPs into 128-dim fp64 vectors.
// ---------------------------------------------------------------------------
__global__ __launch_bounds__(256) void k_collapse64(
    const float* __restrict__ Wpi, const float* __restrict__ bpi,
    const float* __restrict__ Wpo, const float* __restrict__ bpo,
    const float* __restrict__ Wti, const float* __restrict__ bti,
    const float* __restrict__ Wto, const float* __restrict__ bto,
    double* __restrict__ wphid, double* __restrict__ wtaud,
    double* __restrict__ ccd) {
  int tid = threadIdx.x;
  int blk = blockIdx.x;
  if (blk < 16) {
    int r = blk * 16 + (tid >> 4);
    int l = tid & 15;
    double s = 0.;
    if (r < 128) {
      for (int i = 0; i < 32; ++i)
        s += (double)Wpi[r * 512 + l + 16 * i] * (double)Wpo[l + 16 * i];
    } else {
      int rr = r - 128;
      for (int i = 0; i < 16; ++i)
        s += (double)Wti[rr * 256 + l + 16 * i] * (double)Wto[l + 16 * i];
    }
#pragma unroll
    for (int off = 8; off >= 1; off >>= 1) s += __shfl_xor(s, off, 64);
    if (l == 0) {
      if (r < 128) wphid[r] = s;
      else wtaud[r - 128] = s;
    }
  } else {
    int lane = tid & 63;
    if (tid < 64) {
      double p = 0.;
      for (int c = lane; c < 512; c += 64) p += (double)bpi[c] * (double)Wpo[c];
#pragma unroll
      for (int off = 32; off >= 1; off >>= 1) p += __shfl_xor(p, off, 64);
      if (lane == 0) ccd[0] = p + (double)bpo[0];
    } else if (tid < 128) {
      double p = 0.;
      for (int c = lane; c < 256; c += 64) p += (double)bti[c] * (double)Wto[c];
#pragma unroll
      for (int off = 32; off >= 1; off >>= 1) p += __shfl_xor(p, off, 64);
      if (lane == 0) ccd[1] = p + (double)bto[0];
    }
  }
}

// ---------------------------------------------------------------------------
// fp32 GEMM, strict sequential-k fp32 FMA per output element (BLAS-order).
// R1 structure + R9 XOR-swizzled As stores (conflicts 2.36M->0.79M, 54->50us).
// CLOSED: R2 wave-uniform A (3.7x regress), R3 dbuf (neutral), R7 BM=32
// (issue/ILP-bound, not occupancy). Micro-tile >= 4x4 is load-bearing.
// ---------------------------------------------------------------------------
__device__ __forceinline__ void gemm_body(
    const float* __restrict__ A, const float* __restrict__ W,
    const float* __restrict__ bias, float* __restrict__ out,
    int bm, int bn, int mode) {
  __shared__ float As[32][68];
  __shared__ float Bs[32][64];
  const int tid = threadIdx.x;
  const int tx = tid & 15;
  const int ty = tid >> 4;
  float acc[4][4] = {{0.f, 0.f, 0.f, 0.f}};
  for (int k0 = 0; k0 < 512; k0 += 32) {
#pragma unroll
    for (int i = 0; i < 2; ++i) {
      int idx = i * 256 + tid;     // 0..511
      int row = idx >> 3;          // 0..63
      int c4 = (idx & 7) << 2;     // 0..28
      int sw = (idx & 7) << 3;     // swizzle bits 3-5
      int rs = row ^ sw;           // 0..63
      float4 av = *(const float4*)&A[(bm + row) * 512 + k0 + c4];
      As[c4 + 0][rs] = av.x;
      As[c4 + 1][rs] = av.y;
      As[c4 + 2][rs] = av.z;
      As[c4 + 3][rs] = av.w;
    }
#pragma unroll
    for (int i = 0; i < 2; ++i) {
      int idx = i * 256 + tid;     // 0..511
      int br = idx >> 4;           // 0..31
      int bc = (idx & 15) << 2;
      *(float4*)&Bs[br][bc] = *(const float4*)&W[(k0 + br) * 512 + bn + bc];
    }
    __syncthreads();
#pragma unroll
    for (int kk = 0; kk < 32; ++kk) {
      const int sr = ((kk >> 2) & 7) << 3;
      float4 a = *(const float4*)&As[kk][(ty * 4) ^ sr];
      float4 b = *(const float4*)&Bs[kk][tx << 2];
      acc[0][0] = fmaf(a.x, b.x, acc[0][0]);
      acc[0][1] = fmaf(a.x, b.y, acc[0][1]);
      acc[0][2] = fmaf(a.x, b.z, acc[0][2]);
      acc[0][3] = fmaf(a.x, b.w, acc[0][3]);
      acc[1][0] = fmaf(a.y, b.x, acc[1][0]);
      acc[1][1] = fmaf(a.y, b.y, acc[1][1]);
      acc[1][2] = fmaf(a.y, b.z, acc[1][2]);
      acc[1][3] = fmaf(a.y, b.w, acc[1][3]);
      acc[2][0] = fmaf(a.z, b.x, acc[2][0]);
      acc[2][1] = fmaf(a.z, b.y, acc[2][1]);
      acc[2][2] = fmaf(a.z, b.z, acc[2][2]);
      acc[2][3] = fmaf(a.z, b.w, acc[2][3]);
      acc[3][0] = fmaf(a.w, b.x, acc[3][0]);
      acc[3][1] = fmaf(a.w, b.y, acc[3][1]);
      acc[3][2] = fmaf(a.w, b.z, acc[3][2]);
      acc[3][3] = fmaf(a.w, b.w, acc[3][3]);
    }
    __syncthreads();
  }
#pragma unroll
  for (int i = 0; i < 4; ++i) {
    int row = bm + ty * 4 + i;
    float4 r;
    r.x = acc[i][0] + bias[bn + tx * 4 + 0];
    r.y = acc[i][1] + bias[bn + tx * 4 + 1];
    r.z = acc[i][2] + bias[bn + tx * 4 + 2];
    r.w = acc[i][3] + bias[bn + tx * 4 + 3];
    if (mode == 0) {
      *(float4*)&out[row * 512 + bn + tx * 4] = r;
    } else {
      int bb = row >> 10;
      int tt2 = row & 1023;
      int head = bn >> 6;
      *(float4*)&out[(((bb * NH + head) * TT + tt2) << 6) + tx * 4] = r;
    }
  }
}

__global__ __launch_bounds__(256) void k_gemm(
    const float* __restrict__ A, const float* __restrict__ W,
    const float* __restrict__ bias, float* __restrict__ out, int mode) {
  gemm_body(A, W, bias, out, blockIdx.y * 64, blockIdx.x * 64, mode);
}

__global__ __launch_bounds__(256) void k_gemm_qkv(
    const float* __restrict__ A,
    const float* __restrict__ Wq, const float* __restrict__ bq,
    const float* __restrict__ Wk, const float* __restrict__ bk,
    const float* __restrict__ Wv, const float* __restrict__ bv,
    float* __restrict__ Qf, float* __restrict__ Kf, float* __restrict__ Vf) {
  int which = blockIdx.x >> 3;
  int bn = (blockIdx.x & 7) * 64;
  const float* W = (which == 0) ? Wq : (which == 1) ? Wk : Wv;
  const float* b = (which == 0) ? bq : (which == 1) ? bk : bv;
  float* out = (which == 0) ? Qf : (which == 1) ? Kf : Vf;
  gemm_body(A, W, b, out, blockIdx.y * 64, bn, 1);
}

// ---------------------------------------------------------------------------
// Per-token scalars in fp64 — v2 (R8, coalesced LDS staging).
// ---------------------------------------------------------------------------
__global__ __launch_bounds__(256) void k_tokscal64(
    const float* __restrict__ Qg, const float* __restrict__ Kg,
    const double* __restrict__ wphid, const float* __restrict__ Wta,
    const float* __restrict__ Wtb, const double* __restrict__ wtaud,
    double4* __restrict__ sqd4, double4* __restrict__ skd4) {
  __shared__ double wp[128], wa[128], wb[128], wt[128];
  __shared__ float Qs[128][64];
  __shared__ float Ks[128][64];
  const int tid = threadIdx.x;
  if (tid < 128) {
    wp[tid] = wphid[tid];
    wa[tid] = (double)Wta[tid];
    wb[tid] = (double)Wtb[tid];
    wt[tid] = wtaud[tid];
  }
  const int tok0 = blockIdx.x * 128;
#pragma unroll
  for (int i = 0; i < 8; ++i) {
    int idx = i * 256 + tid;          // 0..2047
    int row = idx >> 4;               // 0..127
    int c4 = (idx & 15) << 2;         // 0..60
    *(float4*)&Qs[row][c4] = *(const float4*)&Qg[(size_t)(tok0 + row) * 64 + c4];
    *(float4*)&Ks[row][c4] = *(const float4*)&Kg[(size_t)(tok0 + row) * 64 + c4];
  }
  __syncthreads();
  const int r = tid >> 1;        // token row 0..127
  const int h = tid & 1;         // half: d in [h*32, h*32+32)
  const int dbase = h << 5;
  double sp = 0., sa = 0., sb = 0., st = 0.;
  double kp = 0., ka = 0., kb2 = 0., kt = 0.;
#pragma unroll
  for (int i = 0; i < 32; ++i) {
    int d = dbase + ((i + r) & 31);   // rotated -> conflict-free banks
    double q = (double)Qs[r][d];
    double k = (double)Ks[r][d];
    sp += q * wp[d];
    sa += q * wa[d];
    sb += q * wb[d];
    st += q * wt[d];
    kp += k * wp[64 + d];
    ka += k * wa[64 + d];
    kb2 += k * wb[64 + d];
    kt += k * wt[64 + d];
  }
  sp += __shfl_xor(sp, 1, 64);  sa += __shfl_xor(sa, 1, 64);
  sb += __shfl_xor(sb, 1, 64);  st += __shfl_xor(st, 1, 64);
  kp += __shfl_xor(kp, 1, 64);  ka += __shfl_xor(ka, 1, 64);
  kb2 += __shfl_xor(kb2, 1, 64); kt += __shfl_xor(kt, 1, 64);
  const int tok = tok0 + r;
  if (h == 0) sqd4[tok] = make_double4(sp, sa, sb, st);
  else        skd4[tok] = make_double4(kp, ka, kb2, kt);
}

// ---------------------------------------------------------------------------
// FUSED attention v3 — scores in REGISTERS (no Sc HBM round-trip, no sc LDS).
// Fixes both prior fusion failures: R5 (uncoalesced per-lane K loads) via
// coalesced K-tile staging; R6 (137KB LDS -> 1 block/CU) via register scores
// (LDS = 8KB Q + 66.5KB KT ~ 75KB -> 2 blocks/CU).
//  * Block: 32 q-rows x one bh. Wave wv owns rows wv*8..+7. Lane l holds
//    score v[r][t*4+j] = col t*256 + l*4 + j — EXACTLY k_topk's layout,
//    so the R1-proven selection + fp32 finish run verbatim per row.
//  * K tile (256 rows) staged transposed KT[d][kr^sw], sw=8*((d>>2)&7):
//    coalesced global float4 reads; swizzled stores; compute reads are a
//    lane-permuted contiguous 1KB b128 sweep (conflict-free).
//  * Score rounding: d strictly ascending 0..63, one fmaf per d per element
//    (q.x*k[d4] -> q.y*k[d4+1] -> ...) — bit-identical to k_score.
//  * All v[] indices compile-time (t,r,g,e loops unrolled) — rule #20.
// Grid (32, 16) = 512 blocks, 256 threads.
// ---------------------------------------------------------------------------
__global__ __launch_bounds__(256) void k_attn_f3(
    const float* __restrict__ Qg, const float* __restrict__ Kg,
    const float* __restrict__ Vg, const double4* __restrict__ sqd4,
    const double4* __restrict__ skd4, const double* __restrict__ ccd,
    const float* __restrict__ btaP, const float* __restrict__ btbP,
    float* __restrict__ C) {
  __shared__ float qs[32][64];
  __shared__ float KT[64][260];   // [d][kr^sw], transposed swizzled K tile
  const int bh = blockIdx.y;
  const int q0 = blockIdx.x * 32;
  const int tid = threadIdx.x;
  const int lane = tid & 63;
  const int wv = tid >> 6;

  // stage Q: 32 rows x 64 d, coalesced (2 float4 per thread)
#pragma unroll
  for (int i = 0; i < 2; ++i) {
    int idx = i * 256 + tid;        // 0..511
    int row = idx >> 4;             // 0..31
    int c4 = (idx & 15) << 2;       // 0..60
    *(float4*)&qs[row][c4] =
        *(const float4*)&Qg[(size_t)(bh * TT + q0 + row) * 64 + c4];
  }

  float v[8][16];
#pragma unroll
  for (int r = 0; r < 8; ++r)
#pragma unroll
    for (int s = 0; s < 16; ++s) v[r][s] = 0.f;

#pragma unroll
  for (int t = 0; t < 4; ++t) {
    __syncthreads();   // protect KT (and qs on t=0) before overwrite
    // stage K tile t: 256 rows x 64 d, coalesced (16 float4 per thread)
#pragma unroll
    for (int i = 0; i < 16; ++i) {
      int idx = i * 256 + tid;      // 0..4095
      int kr = idx >> 4;            // 0..255
      int d4 = (idx & 15) << 2;     // 0..60
      float4 kv =
          *(const float4*)&Kg[(size_t)(bh * TT + t * 256 + kr) * 64 + d4];
      int krs = kr ^ (((d4 >> 2) & 7) << 3);
      KT[d4 + 0][krs] = kv.x;
      KT[d4 + 1][krs] = kv.y;
      KT[d4 + 2][krs] = kv.z;
      KT[d4 + 3][krs] = kv.w;
    }
    __syncthreads();
    // compute: 16 d4-blocks; 4 K b128 reads serve 8 rows x 16 FMA
#pragma unroll 1
    for (int d4 = 0; d4 < 64; d4 += 4) {
      const int cbase = (lane << 2) ^ (((d4 >> 2) & 7) << 3);
      float4 k0 = *(const float4*)&KT[d4 + 0][cbase];
      float4 k1 = *(const float4*)&KT[d4 + 1][cbase];
      float4 k2 = *(const float4*)&KT[d4 + 2][cbase];
      float4 k3 = *(const float4*)&KT[d4 + 3][cbase];
#pragma unroll
      for (int r = 0; r < 8; ++r) {
        float4 q4 = *(const float4*)&qs[wv * 8 + r][d4];
        // per accumulator: d4+0 -> d4+1 -> d4+2 -> d4+3 (d ascending)
        v[r][t * 4 + 0] = fmaf(q4.x, k0.x, v[r][t * 4 + 0]);
        v[r][t * 4 + 1] = fmaf(q4.x, k0.y, v[r][t * 4 + 1]);
        v[r][t * 4 + 2] = fmaf(q4.x, k0.z, v[r][t * 4 + 2]);
        v[r][t * 4 + 3] = fmaf(q4.x, k0.w, v[r][t * 4 + 3]);
        v[r][t * 4 + 0] = fmaf(q4.y, k1.x, v[r][t * 4 + 0]);
        v[r][t * 4 + 1] = fmaf(q4.y, k1.y, v[r][t * 4 + 1]);
        v[r][t * 4 + 2] = fmaf(q4.y, k1.z, v[r][t * 4 + 2]);
        v[r][t * 4 + 3] = fmaf(q4.y, k1.w, v[r][t * 4 + 3]);
        v[r][t * 4 + 0] = fmaf(q4.z, k2.x, v[r][t * 4 + 0]);
        v[r][t * 4 + 1] = fmaf(q4.z, k2.y, v[r][t * 4 + 1]);
        v[r][t * 4 + 2] = fmaf(q4.z, k2.z, v[r][t * 4 + 2]);
        v[r][t * 4 + 3] = fmaf(q4.z, k2.w, v[r][t * 4 + 3]);
        v[r][t * 4 + 0] = fmaf(q4.w, k3.x, v[r][t * 4 + 0]);
        v[r][t * 4 + 1] = fmaf(q4.w, k3.y, v[r][t * 4 + 1]);
        v[r][t * 4 + 2] = fmaf(q4.w, k3.z, v[r][t * 4 + 2]);
        v[r][t * 4 + 3] = fmaf(q4.w, k3.w, v[r][t * 4 + 3]);
      }
    }
  }

  // ---- selection + fp32 finish, verbatim R1-proven logic, per row ----
  const double cphi = ccd[0];
  const double ctau = ccd[1];
  const double bta0 = (double)btaP[0];
  const double btb0 = (double)btbP[0];
  const int bb = bh >> 3;
  const int hh = bh & 7;
  const float* Vbh = Vg + (size_t)bh * (TT * 64);
  const int lbase = lane << 2;
#pragma unroll
  for (int r = 0; r < 8; ++r) {
    const int qa = q0 + wv * 8 + r;
    float gv[4];
    int gi[4];
#pragma unroll
    for (int g = 0; g < 4; ++g) {
      float nv = v[r][4 * g];
      int ne = 0;
#pragma unroll
      for (int e = 1; e < 4; ++e) {
        if (v[r][4 * g + e] > nv) { nv = v[r][4 * g + e]; ne = e; }
      }
      gv[g] = nv;
      gi[g] = (g << 8) | lbase | ne;
    }
    int myk = 0;
#pragma unroll 1
    for (int it = 0; it < NTOPK; ++it) {
      float cv = gv[0];
      int ci = gi[0];
#pragma unroll
      for (int g = 1; g < 4; ++g) {
        if (gv[g] > cv) { cv = gv[g]; ci = gi[g]; }
      }
      float M = cv;
#pragma unroll
      for (int off = 32; off >= 1; off >>= 1)
        M = fmaxf(M, __shfl_xor(M, off, 64));
      unsigned long long tied = __ballot(cv == M);
      int J;
      if (__popcll(tied) == 1) {
        int src = __ffsll(tied) - 1;
        J = __builtin_amdgcn_readfirstlane(__shfl(ci, src, 64));
      } else {
        int cj = (cv == M) ? ci : 0x7FFFFFFF;
#pragma unroll
        for (int off = 32; off >= 1; off >>= 1) {
          int oj = __shfl_xor(cj, off, 64);
          cj = (oj < cj) ? oj : cj;
        }
        J = __builtin_amdgcn_readfirstlane(cj);
      }
      if (lane == it) myk = J;
      const int owner = (J >> 2) & 63;
      const int g2 = J >> 8;
      const int e2 = J & 3;
      const bool isown = (lane == owner);
#pragma unroll
      for (int g = 0; g < 4; ++g) {
        if (g == g2) {  // uniform branch
#pragma unroll
          for (int e = 0; e < 4; ++e) {
            if (e == e2) v[r][4 * g + e] = isown ? -INFINITY : v[r][4 * g + e];
          }
          float nv = v[r][4 * g];
          int ne = 0;
#pragma unroll
          for (int e = 1; e < 4; ++e) {
            if (v[r][4 * g + e] > nv) { nv = v[r][4 * g + e]; ne = e; }
          }
          gv[g] = nv;
          gi[g] = (g << 8) | lbase | ne;
        }
      }
    }
    // fp32 finish (identical to k_topk's proven path)
    double4 sq = sqd4[(size_t)bh * TT + qa];
    float logit = -INFINITY;
    if (lane < 16) {
      double4 sk = skd4[bh * TT + myk];
      float xs = (float)(sq.x + sk.x + cphi);
      float ta = (float)(sq.y + sk.y + bta0);
      float tb = (float)(sq.z + sk.z + btb0);
      float tl = (float)(sq.w + sk.w + ctau);
      float phi = 1.f / (1.f + __expf(-xs));
      float ti = 1.f / (1.f + __expf(-(ta + tb)));          // T_SCALAR = 1
      float tau = fmaxf(tl, 0.f) + log1pf(__expf(-fabsf(tl))) + 1e-6f;
      logit = phi / tau * (1.f - __expf(-tau * ti));
    }
    float m = logit;
#pragma unroll
    for (int off = 8; off >= 1; off >>= 1) m = fmaxf(m, __shfl_xor(m, off, 64));
    float e = (lane < 16) ? __expf(logit - m) : 0.f;
    float ssum = e;
#pragma unroll
    for (int off = 8; off >= 1; off >>= 1) ssum += __shfl_xor(ssum, off, 64);
    float w = e / ssum;
    float outv = 0.f;
#pragma unroll
    for (int k2 = 0; k2 < NTOPK; ++k2) {
      float wk = __shfl(w, k2, 64);
      int ik = __shfl(myk, k2, 64);
      outv = fmaf(wk, Vbh[(size_t)ik * 64 + lane], outv);
    }
    C[(bb * TT + qa) * 512 + hh * 64 + lane] = outv;
  }
}

// ---------------------------------------------------------------------------
extern "C" void kernel_launch(void* const* d_in, const int* in_sizes, int n_in,
                              void* d_out, int out_size, void* d_ws, size_t ws_size,
                              hipStream_t stream) {
  (void)in_sizes; (void)n_in; (void)out_size; (void)ws_size;
  const float* x   = (const float*)d_in[0];
  const float* Wq  = (const float*)d_in[1];
  const float* bq  = (const float*)d_in[2];
  const float* Wk  = (const float*)d_in[3];
  const float* bk  = (const float*)d_in[4];
  const float* Wv  = (const float*)d_in[5];
  const float* bv  = (const float*)d_in[6];
  const float* Wo  = (const float*)d_in[7];
  const float* bo  = (const float*)d_in[8];
  const float* Wpi = (const float*)d_in[9];
  const float* bpi = (const float*)d_in[10];
  const float* Wpo = (const float*)d_in[11];
  const float* bpo = (const float*)d_in[12];
  const float* Wta = (const float*)d_in[13];
  const float* bta = (const float*)d_in[14];
  const float* Wtb = (const float*)d_in[15];
  const float* btb = (const float*)d_in[16];
  const float* Wti = (const float*)d_in[17];
  const float* bti = (const float*)d_in[18];
  const float* Wto = (const float*)d_in[19];
  const float* bto = (const float*)d_in[20];

  double* wsd = (double*)d_ws;
  double4* sqd4 = (double4*)wsd;             // 65536 doubles
  double4* skd4 = (double4*)(wsd + 65536);   // 65536 doubles
  double* wphid = wsd + 131072;              // 128
  double* wtaud = wsd + 131200;              // 128
  double* ccd   = wsd + 131328;              // 2 (pad to 131332)
  float* fs = (float*)(wsd + 131332);
  float* Qf = fs;                  // 1,048,576 floats
  float* Kf = fs + 1048576;
  float* Vf = fs + 2097152;
  float* Cf = fs + 3145728;

  hipLaunchKernelGGL(k_collapse64, dim3(17), dim3(256), 0, stream,
                     Wpi, bpi, Wpo, bpo, Wti, bti, Wto, bto, wphid, wtaud, ccd);
  hipLaunchKernelGGL(k_gemm_qkv, dim3(24, 32), dim3(256), 0, stream,
                     x, Wq, bq, Wk, bk, Wv, bv, Qf, Kf, Vf);
  hipLaunchKernelGGL(k_tokscal64, dim3(NTOK / 128), dim3(256), 0, stream,
                     Qf, Kf, wphid, Wta, Wtb, wtaud, sqd4, skd4);
  hipLaunchKernelGGL(k_attn_f3, dim3(32, NBH), dim3(256), 0, stream,
                     Qf, Kf, Vf, sqd4, skd4, ccd, bta, btb, Cf);
  hipLaunchKernelGGL(k_gemm, dim3(8, 32), dim3(256), 0, stream,
                     Cf, Wo, bo, (float*)d_out, 0);
}